// Round 11
// baseline (271.395 us; speedup 1.0000x reference)
//
#include <hip/hip_runtime.h>

typedef float v4f __attribute__((ext_vector_type(4)));

#define NB   32     // batch
#define NT   8      // timesteps
#define NC   128    // channels
#define NQ   256    // float4s per (H*W)=1024 plane
#define CRED 32     // C/red

// Cross-block mean publish: each channel mean (double) is split into two
// 64-bit words:  word = (seq << 32) | 32-bit-half-of-double-bits, seq = t+1.
// Data and version share ONE atomic location -> freshness is self-validating
// (no reliance on store-ack == LLC-complete; that was the R0 failure).
// One buffer slice PER STEP (write-once -> no WAR hazard) -> no arrive
// barrier: consumers spin directly on the data words. Zeroed per launch so
// seq=0 is invalid across graph replays.
#define NWORDS (NT * NB * NC * 2)   // step x batch x channel x {lo,hi}

__device__ unsigned long long g_xw[NWORDS];          // (seq<<32 | half) words

__global__ __launch_bounds__(256)
void lif_init() {
    int i = threadIdx.x + blockIdx.x * blockDim.x;
    if (i < NWORDS) g_xw[i] = 0ull;
}

// Raw barrier: LDS-only drain (lgkmcnt), NO vmcnt(0). Fused into one asm so
// no LDS access can be hoisted between the wait and the barrier. Critically,
// waves waiting here do NOT drain their outstanding nontemporal stores.
#define LDS_BARRIER() asm volatile("s_waitcnt lgkmcnt(0)\n\ts_barrier" ::: "memory")

// ---------------------------------------------------------------------------
// R4: WAVE-SPECIALIZED POLL. R3's counters (89 us) showed publish-first only
// bought 8 us. Real culprit: vmcnt retires IN ORDER, and every poll
// iteration's s_waitcnt vmcnt(0) therefore waits for the wave's OWN phase-B
// spike stores (16 KB) whose acks are throttled by the GPU-wide HBM write
// drain (16.8 MB/step). All waves were paying store-drain inside the sync
// window, serializing memory with the inter-block chain.
// Now: only WAVE 0 polls (4 words/lane, seq-validated) + runs the MLP.
// Waves 1-3 issue prefetch loads FIRST (so next phase A retires at
// vmcnt(4), never draining stores), then fire-and-forget their spike
// stores, then wait at an LDS-only barrier -- 75% of write traffic is never
// on any wait path. Wave 0's poll drains only its own 4 KB, hidden inside
// the sibling-skew window it must wait out anyway.
// MLP runs on the same lanes (wave-0 lanes 0-31) with the same cc-ascending
// summation, same reduce, same sigmoid -> spikes and tau bit-identical to
// the harness-verified R2/R3 kernels.
// Co-residency: VGPR < 128 @ __launch_bounds__(256,4) -> 4 blocks/CU
// guaranteed resident for all 1024 blocks; spin cannot deadlock.
// ---------------------------------------------------------------------------
__global__ __launch_bounds__(256, 4)
void dynamic_lif(const float* __restrict__ x,
                 const float* __restrict__ w1,
                 const float* __restrict__ b1,
                 const float* __restrict__ w2,
                 const float* __restrict__ b2,
                 float* __restrict__ out)
{
    const int bid = blockIdx.x;          // 0..1023
    const int b   = bid >> 5;            // batch
    const int c0  = (bid & 31) << 2;     // first of 4 channels
    const int tid = threadIdx.x;
    const int wv  = tid >> 6;
    const int ln  = tid & 63;

    __shared__ double       s_part[4][4];
    __shared__ unsigned int s_w[256];    // fetched 32-bit halves (wave 0 only)
    __shared__ float        s_tau;

    const v4f* __restrict__ x4 = (const v4f*)x;
    v4f* __restrict__ o4       = (v4f*)out;

    v4f mem[4];
    #pragma unroll
    for (int p = 0; p < 4; ++p) mem[p] = (v4f){0.f, 0.f, 0.f, 0.f};

    float tau = 0.5f;                    // TAU0

    v4f xv[4];
    #pragma unroll
    for (int p = 0; p < 4; ++p)
        xv[p] = __builtin_nontemporal_load(x4 + ((b * NT + 0) * NC + c0 + p) * NQ + tid);

    for (int t = 0; t < NT; ++t) {
        // ---- phase A: fma + plane-sum (no stores); mem keeps PRE-reset ----
        double psum[4];
        #pragma unroll
        for (int p = 0; p < 4; ++p) {
            v4f m = mem[p];
            m.x = fmaf(m.x, tau, xv[p].x);
            m.y = fmaf(m.y, tau, xv[p].y);
            m.z = fmaf(m.z, tau, xv[p].z);
            m.w = fmaf(m.w, tau, xv[p].w);
            psum[p] = ((double)m.x + (double)m.y) + ((double)m.z + (double)m.w);
            mem[p] = m;
        }

        #pragma unroll
        for (int p = 0; p < 4; ++p) {
            double s = psum[p];
            #pragma unroll
            for (int off = 32; off > 0; off >>= 1) s += __shfl_down(s, off);
            if (ln == 0) s_part[p][wv] = s;
        }
        LDS_BARRIER();                   // B1: s_part visible to wave 0

        if (t == NT - 1) {
            // last step: nothing consumes the means; just emit spikes
            #pragma unroll
            for (int p = 0; p < 4; ++p) {
                v4f m = mem[p];
                v4f sp;
                sp.x = (m.x > 1.0f) ? 1.0f : 0.0f;   // zif(mem-1): exact
                sp.y = (m.y > 1.0f) ? 1.0f : 0.0f;
                sp.z = (m.z > 1.0f) ? 1.0f : 0.0f;
                sp.w = (m.w > 1.0f) ? 1.0f : 0.0f;
                __builtin_nontemporal_store(sp,
                    o4 + ((b * NT + t) * NC + c0 + p) * NQ + tid);
            }
            break;
        }

        if (wv == 0) {
            // ---- wave 0: publish (FIRST VMEM of the step) ----
            if (ln < 4) {
                double s = (s_part[ln][0] + s_part[ln][1]) +
                           (s_part[ln][2] + s_part[ln][3]);
                double mean = s * (1.0 / 1024.0);
                unsigned long long bits = __double_as_longlong(mean);
                unsigned long long tag  = ((unsigned long long)(t + 1)) << 32;
                const int base = ((t * NB + b) * NC + c0 + ln) * 2;
                __hip_atomic_store(&g_xw[base + 0], tag | (bits & 0xffffffffull),
                                   __ATOMIC_RELAXED, __HIP_MEMORY_SCOPE_AGENT);
                __hip_atomic_store(&g_xw[base + 1], tag | (bits >> 32),
                                   __ATOMIC_RELAXED, __HIP_MEMORY_SCOPE_AGENT);
            }
            // prefetch (loads before stores in this wave's VMEM order)
            #pragma unroll
            for (int p = 0; p < 4; ++p)
                xv[p] = __builtin_nontemporal_load(
                    x4 + ((b * NT + (t + 1)) * NC + c0 + p) * NQ + tid);
            // own spike stores (only 4 KB; drain hides in sibling window)
            #pragma unroll
            for (int p = 0; p < 4; ++p) {
                v4f m = mem[p];
                v4f sp;
                sp.x = (m.x > 1.0f) ? 1.0f : 0.0f;
                sp.y = (m.y > 1.0f) ? 1.0f : 0.0f;
                sp.z = (m.z > 1.0f) ? 1.0f : 0.0f;
                sp.w = (m.w > 1.0f) ? 1.0f : 0.0f;
                __builtin_nontemporal_store(sp,
                    o4 + ((b * NT + t) * NC + c0 + p) * NQ + tid);
                m.x = (m.x > 1.0f) ? 0.0f : m.x;
                m.y = (m.y > 1.0f) ? 0.0f : m.y;
                m.z = (m.z > 1.0f) ? 0.0f : m.z;
                m.w = (m.w > 1.0f) ? 0.0f : m.w;
                mem[p] = m;
            }

            // ---- seq-validated poll: 4 words per lane (wave 0 only) ----
            {
                const int wbase = (t * NB + b) * NC * 2;
                const unsigned int want = (unsigned int)(t + 1);
                #pragma unroll
                for (int j = 0; j < 4; ++j) {
                    unsigned long long w;
                    for (;;) {
                        w = __hip_atomic_load(&g_xw[wbase + ln + 64 * j],
                                              __ATOMIC_RELAXED,
                                              __HIP_MEMORY_SCOPE_AGENT);
                        if ((unsigned int)(w >> 32) == want) break;
                        __builtin_amdgcn_s_sleep(1);
                    }
                    s_w[ln + 64 * j] = (unsigned int)w;
                }
            }
            // within-wave LDS write->read ordering (no barrier needed)
            asm volatile("s_waitcnt lgkmcnt(0)" ::: "memory");

            // tiny MLP (128->32->1) on lanes 0-31; identical order to the
            // verified kernel: cc = 0..127 ascending, exact double bits.
            double e = 0.0;
            if (ln < CRED) {
                const v4f* __restrict__ w1v = (const v4f*)(w1 + ln * NC);
                double acc = (double)b1[ln];
                #pragma unroll
                for (int q = 0; q < NC / 4; ++q) {
                    v4f wq = w1v[q];
                    #pragma unroll
                    for (int k = 0; k < 4; ++k) {
                        const int c = 4 * q + k;
                        unsigned long long bits =
                            ((unsigned long long)s_w[2 * c + 1] << 32) | s_w[2 * c];
                        double xm = __longlong_as_double(bits);
                        acc += xm * (double)((k == 0) ? wq.x : (k == 1) ? wq.y
                                             : (k == 2) ? wq.z : wq.w);
                    }
                }
                double emb = acc > 0.0 ? acc : 0.0;
                e = emb * (double)w2[ln];
            }
            #pragma unroll
            for (int off = 32; off > 0; off >>= 1) e += __shfl_down(e, off);
            if (ln == 0) {
                double z = e + (double)b2[0];
                s_tau = (float)(1.0 / (1.0 + exp(-z)));
            }
        } else {
            // ---- waves 1-3: prefetch FIRST (loads ahead of stores so the
            // next phase A retires at vmcnt(4) without draining stores),
            // then fire-and-forget spike stores; never poll, never drain.
            #pragma unroll
            for (int p = 0; p < 4; ++p)
                xv[p] = __builtin_nontemporal_load(
                    x4 + ((b * NT + (t + 1)) * NC + c0 + p) * NQ + tid);
            #pragma unroll
            for (int p = 0; p < 4; ++p) {
                v4f m = mem[p];
                v4f sp;
                sp.x = (m.x > 1.0f) ? 1.0f : 0.0f;
                sp.y = (m.y > 1.0f) ? 1.0f : 0.0f;
                sp.z = (m.z > 1.0f) ? 1.0f : 0.0f;
                sp.w = (m.w > 1.0f) ? 1.0f : 0.0f;
                __builtin_nontemporal_store(sp,
                    o4 + ((b * NT + t) * NC + c0 + p) * NQ + tid);
                m.x = (m.x > 1.0f) ? 0.0f : m.x;
                m.y = (m.y > 1.0f) ? 0.0f : m.y;
                m.z = (m.z > 1.0f) ? 0.0f : m.z;
                m.w = (m.w > 1.0f) ? 0.0f : m.w;
                mem[p] = m;
            }
        }

        LDS_BARRIER();                   // B2: s_tau visible to all waves
        tau = s_tau;
    }
}

extern "C" void kernel_launch(void* const* d_in, const int* in_sizes, int n_in,
                              void* d_out, int out_size, void* d_ws, size_t ws_size,
                              hipStream_t stream) {
    const float* x  = (const float*)d_in[0];
    const float* w1 = (const float*)d_in[1];
    const float* b1 = (const float*)d_in[2];
    const float* w2 = (const float*)d_in[3];
    const float* b2 = (const float*)d_in[4];
    float* out      = (float*)d_out;

    // zero the seq-tagged word buffer (stream-ordered before the main kernel)
    hipLaunchKernelGGL(lif_init, dim3((NWORDS + 255) / 256), dim3(256),
                       0, stream);
    // plain launch — no cooperative protocol overhead
    hipLaunchKernelGGL(dynamic_lif, dim3(NB * NC / 4), dim3(256), 0, stream,
                       x, w1, b1, w2, b2, out);
}